// Round 4
// baseline (1476.687 us; speedup 1.0000x reference)
//
#include <hip/hip_runtime.h>
#include <cstdint>
#include <cstddef>

#define B_TOT 2048
#define T_TOT 50
#define NIN   620
#define NH    620
#define NCLS  11

// OpenBLAS sgemm K-panel size (SGEMM_DEFAULT_Q). Per-element arithmetic:
// C = fl( fl(chain k<KC) + fl(chain k>=KC) ), each chain single-accumulator
// ascending-k fmaf. THIS RECIPE IS BITWISE-VERIFIED (R4, absmax=0) — do not
// change summation order, only scheduling.
#define KC 384

// GEMM tiling: 128x128 block tile, 8x8 microtile, KB=32.
// R5: lane remaps -> all LDS access uniform 2-way (free). Conflicts 1.4e8->2e7.
// R6: FAILED — A+B reg prefetch under (256,4): allocator chose 64 VGPR and
//     spilled (FETCH 1.16->2.49 GB). Reverted.
// R7: A-only prefetch under (256,3): VGPR 80 -> allocator SANK the prefetch
//     (80 can't hold acc64+pa16+frags), only -3.8%. FETCH clean.
// R8: (256,4) with A-only prefetch: demand ~100-110 < 128 cap -> prefetch
//     can stay live AND 4 blocks/CU if LDS permits.
//     TRIPWIRE: VGPR_Count must be 96..128 (not 64); FETCH ~1.07e6 KB.
#define BM 128
#define BN 128
#define KB 32   // KC % KB == 0 -> split is tile-aligned

__global__ __launch_bounds__(256, 4)
void gemm_relu_kernel(const float* __restrict__ X,
                      const float* __restrict__ W1,
                      float* __restrict__ Z,
                      int t0, int ct)
{
    __shared__ float As[KB][BM + 4];
    __shared__ float Bs[KB][BN + 4];

    const int tid = threadIdx.x;
    const int n0 = blockIdx.x * BN;
    const int m0 = blockIdx.y * BM;
    const int tx = tid & 15;   // n direction: cols tx*4..tx*4+3 and 64+tx*4..
    const int ty = tid >> 4;   // m direction, 8 rows each

    // Staging: tile = 128 rows x 8 k-quads = 1024 float4 tasks, 4 per thread.
    // Per wave: 16 consecutive rows x 4 low k-quads (64B contiguous/row).
    // 32-bit element offsets (X = 63.5M floats < 2^31).
    int a_off[4], b_off[4];
    int s_row[4], s_kl[4], b_ok[4];
#pragma unroll
    for (int it = 0; it < 4; ++it) {
        int task = tid + it * 256;
        int row  = (task >> 2) & 127;                  // 0..127
        int kl   = (task >> 9) * 16 + (task & 3) * 4;  // 0..28
        s_row[it] = row;
        s_kl[it]  = kl;
        int m  = m0 + row;
        int bb = m / ct;
        int dt = m - bb * ct;
        a_off[it] = (bb * T_TOT + (t0 + dt)) * NIN + kl;
        int n = n0 + row;
        b_off[it] = n * NIN + kl;
        b_ok[it]  = (n < NH);
    }

    float acc[8][8];
#pragma unroll
    for (int i = 0; i < 8; ++i)
#pragma unroll
        for (int j = 0; j < 8; ++j) acc[i][j] = 0.0f;

    const int zc0 = n0 + tx * 4;        // cols for acc[i][0..3]
    const int zc1 = n0 + 64 + tx * 4;   // cols for acc[i][4..7]

    // A-prefetch registers (in flight across the compute phase).
    float4 pa[4];

    // ---- prologue: load tile k0=0 (A unconditional: kl<=28<620), commit to
    // LDS (no barrier needed before the writes: LDS not yet read by anyone).
#pragma unroll
    for (int it = 0; it < 4; ++it) {
        pa[it] = *(const float4*)(X + a_off[it]);
        float4 bv = make_float4(0.f, 0.f, 0.f, 0.f);
        if (b_ok[it]) bv = *(const float4*)(W1 + b_off[it]);
        As[s_kl[it] + 0][s_row[it]] = pa[it].x;
        As[s_kl[it] + 1][s_row[it]] = pa[it].y;
        As[s_kl[it] + 2][s_row[it]] = pa[it].z;
        As[s_kl[it] + 3][s_row[it]] = pa[it].w;
        Bs[s_kl[it] + 0][s_row[it]] = bv.x;
        Bs[s_kl[it] + 1][s_row[it]] = bv.y;
        Bs[s_kl[it] + 2][s_row[it]] = bv.z;
        Bs[s_kl[it] + 3][s_row[it]] = bv.w;
    }

    for (int k0 = 0; k0 < NIN; k0 += KB) {
        __syncthreads();   // LDS tile (k0) visible to all waves

        const int k0n = k0 + KB;
        const bool has_next = (k0n < NIN);

        // ---- issue next tile's A loads (X latency hides under compute)
        if (has_next) {
#pragma unroll
            for (int it = 0; it < 4; ++it) {
                pa[it] = make_float4(0.f, 0.f, 0.f, 0.f);
                if (k0n + s_kl[it] < NIN)
                    pa[it] = *(const float4*)(X + a_off[it] + k0n);
            }
        }

        // ---- compute: ascending k, 64 fma per kk
#pragma unroll 8
        for (int kk = 0; kk < KB; ++kk) {
            float a[8], b[8];
            *(float4*)&a[0] = *(const float4*)&As[kk][ty * 8];
            *(float4*)&a[4] = *(const float4*)&As[kk][ty * 8 + 4];
            *(float4*)&b[0] = *(const float4*)&Bs[kk][tx * 4];
            *(float4*)&b[4] = *(const float4*)&Bs[kk][64 + tx * 4];
#pragma unroll
            for (int i = 0; i < 8; ++i)
#pragma unroll
                for (int j = 0; j < 8; ++j)
                    acc[i][j] = fmaf(a[i], b[j], acc[i][j]);
        }

        // ---- panel boundary: dump chain-A raw to Z, zero accs (uniform branch)
        if (k0 + KB == KC) {
#pragma unroll
            for (int i = 0; i < 8; ++i) {
                float* zr = Z + (size_t)(m0 + ty * 8 + i) * NH;
                if (zc0 < NH)
                    *(float4*)(zr + zc0) = make_float4(acc[i][0], acc[i][1],
                                                       acc[i][2], acc[i][3]);
                if (zc1 < NH)
                    *(float4*)(zr + zc1) = make_float4(acc[i][4], acc[i][5],
                                                       acc[i][6], acc[i][7]);
            }
#pragma unroll
            for (int i = 0; i < 8; ++i)
#pragma unroll
                for (int j = 0; j < 8; ++j) acc[i][j] = 0.0f;
            // stores drain before epilogue readback via L2 (same thread).
        }

        __syncthreads();   // all waves done READING LDS tile (k0)

        // ---- commit: load B (L2-resident, short stall) + write A,B to LDS
        if (has_next) {
            float4 nb[4];
#pragma unroll
            for (int it = 0; it < 4; ++it) {
                nb[it] = make_float4(0.f, 0.f, 0.f, 0.f);
                if (b_ok[it] && (k0n + s_kl[it] < NIN))
                    nb[it] = *(const float4*)(W1 + b_off[it] + k0n);
            }
#pragma unroll
            for (int it = 0; it < 4; ++it) {
                As[s_kl[it] + 0][s_row[it]] = pa[it].x;
                As[s_kl[it] + 1][s_row[it]] = pa[it].y;
                As[s_kl[it] + 2][s_row[it]] = pa[it].z;
                As[s_kl[it] + 3][s_row[it]] = pa[it].w;
                Bs[s_kl[it] + 0][s_row[it]] = nb[it].x;
                Bs[s_kl[it] + 1][s_row[it]] = nb[it].y;
                Bs[s_kl[it] + 2][s_row[it]] = nb[it].z;
                Bs[s_kl[it] + 3][s_row[it]] = nb[it].w;
            }
        }
    }

    // ---- epilogue: merge panels (one rounded add), relu, store
#pragma unroll
    for (int i = 0; i < 8; ++i) {
        float* zr = Z + (size_t)(m0 + ty * 8 + i) * NH;
        if (zc0 < NH) {
            float4 p = *(const float4*)(zr + zc0);   // chain A
            float4 v;
            v.x = fmaxf(__fadd_rn(p.x, acc[i][0]), 0.0f);
            v.y = fmaxf(__fadd_rn(p.y, acc[i][1]), 0.0f);
            v.z = fmaxf(__fadd_rn(p.z, acc[i][2]), 0.0f);
            v.w = fmaxf(__fadd_rn(p.w, acc[i][3]), 0.0f);
            *(float4*)(zr + zc0) = v;
        }
        if (zc1 < NH) {
            float4 p = *(const float4*)(zr + zc1);   // chain A
            float4 v;
            v.x = fmaxf(__fadd_rn(p.x, acc[i][4]), 0.0f);
            v.y = fmaxf(__fadd_rn(p.y, acc[i][5]), 0.0f);
            v.z = fmaxf(__fadd_rn(p.z, acc[i][6]), 0.0f);
            v.w = fmaxf(__fadd_rn(p.w, acc[i][7]), 0.0f);
            *(float4*)(zr + zc1) = v;
        }
    }
}

// ---------------------------------------------------------------------------
// Phase B: recurrence, fp32, np-bitwise.
// R8: PACK 2 BATCHES PER WAVE. snn was LDS-pipe instruction bound
// (~192 ds_read_b128/wave/dt x 8 waves/CU ~ 300us). Lanes (0-10,11-21) =
// (b0,b1) panel A; (32-42,43-53) = (b0,b1) panel B. The b-pair reads the
// SAME W2s addresses (LDS broadcast = free), so the same 192 instrs serve
// 2 b's; waves/CU 8->4 -> per-CU LDS demand halves. Rows padded: 4-float
// hole at the KC split + stride 628 (==20 mod 32) -> w4 conflicts 4->~2way.
// Per-(b,cls,panel) fmaf chains, values and order UNCHANGED -> bitwise.
// ---------------------------------------------------------------------------
#define WPB 4            // waves per block
#define BPW 2            // batches (b) per wave
#define BPB (WPB*BPW)    // 8 b per block -> grid 256
#define SROW 628         // padded row stride: [0..383][pad4][388..623][pad4]
#define QB_B 97          // panel-B quad base in padded row (float 388)

__global__ __launch_bounds__(256)
void snn_kernel(const float* __restrict__ Z,
                const float* __restrict__ W2,
                float* __restrict__ state,
                float* __restrict__ out,
                int t0, int ct)
{
    __shared__ float W2s[NCLS][SROW];        // 27.0 KB
    __shared__ float Ss[WPB * BPW][SROW];    // 19.6 KB

    const int tid = threadIdx.x;
    // stage W2 with the split pad
    for (int i = tid; i < NCLS * NH; i += 256) {
        int c = i / NH;
        int k = i - c * NH;
        W2s[c][k + (k >= KC ? 4 : 0)] = W2[i];
    }
    __syncthreads();

    const int lane = tid & 63;
    const int wv   = tid >> 6;
    const int half = lane >> 5;          // 0 = panel A, 1 = panel B
    const int l5   = lane & 31;
    const int sub  = (l5 >= NCLS) ? 1 : 0;   // which b of the wave's pair
    const int cls  = l5 - sub * NCLS;        // valid when l5 < 22
    const int lact = (l5 < 2 * NCLS);
    const int bb   = blockIdx.x * BPB + wv * BPW;   // wave's first b

    float* st_h1m = state;
    float* st_h1s = state + (size_t)B_TOT * NH;
    float* st_h2m = state + (size_t)2 * B_TOT * NH;
    float* st_h2s = st_h2m + (size_t)B_TOT * NCLS;
    float* st_acc = st_h2s + (size_t)B_TOT * NCLS;

    float h1m[20], h1s[20];
    float h2m = 0.f, h2s = 0.f, acc = 0.f;   // (half==0, l5<22) owns (bb+sub, cls)

    if (t0 == 0) {
#pragma unroll
        for (int i = 0; i < 20; ++i) { h1m[i] = 0.f; h1s[i] = 0.f; }
    } else {
#pragma unroll
        for (int u = 0; u < 2; ++u)
#pragma unroll
        for (int i = 0; i < 10; ++i) {
            int k = i * 64 + lane;
            int idx = u * 10 + i;
            if (k < NH) {
                h1m[idx] = st_h1m[(size_t)(bb + u) * NH + k];
                h1s[idx] = st_h1s[(size_t)(bb + u) * NH + k];
            } else { h1m[idx] = 0.f; h1s[idx] = 0.f; }
        }
        if (half == 0 && lact) {
            int b2 = bb + sub;
            h2m = st_h2m[(size_t)b2 * NCLS + cls];
            h2s = st_h2s[(size_t)b2 * NCLS + cls];
            acc = st_acc[(size_t)b2 * NCLS + cls];
        }
    }

    const int qcnt = half ? ((NH - KC) / 4) : (KC / 4);   // 59 : 96

    // ---- z double-buffer: preload dt=0 for both b's
    float zr[20];
#pragma unroll
    for (int u = 0; u < 2; ++u) {
        const float* z0 = Z + (size_t)(bb + u) * ct * NH;
#pragma unroll
        for (int i = 0; i < 10; ++i) {
            int k = i * 64 + lane;
            zr[u * 10 + i] = (k < NH) ? z0[k] : 0.0f;
        }
    }

    for (int dt = 0; dt < ct; ++dt) {
        // layer-1 membrane for both b's (np op order, each op rounded)
#pragma unroll
        for (int u = 0; u < 2; ++u)
#pragma unroll
        for (int i = 0; i < 10; ++i) {
            int k = i * 64 + lane;
            if (k < NH) {
                int idx = u * 10 + i;
                float dec = __fmul_rn(__fmul_rn(h1m[idx], 0.2f), (1.0f - h1s[idx]));
                float m = __fadd_rn(dec, zr[idx]);
                float s = (m > 0.5f) ? 1.0f : 0.0f;
                h1m[idx] = m; h1s[idx] = s;
                Ss[wv * BPW + u][k + (k >= KC ? 4 : 0)] = s;   // pad cond: i>=6, static
            }
        }
        __syncthreads();

        // ---- issue dt+1's z loads (in flight under layer-2)
        if (dt + 1 < ct) {
#pragma unroll
            for (int u = 0; u < 2; ++u) {
                const float* zn = Z + ((size_t)(bb + u) * ct + (dt + 1)) * NH;
#pragma unroll
                for (int i = 0; i < 10; ++i) {
                    int k = i * 64 + lane;
                    if (k < NH) zr[u * 10 + i] = zn[k];
                }
            }
        }

        // layer-2: lane (half, sub, cls) runs panel-half's chain for b=bb+sub.
        // Batched loads + fmas in ascending-k order: bitwise identical chain.
        float csum = 0.0f;
        if (lact) {
            const float4* w4 = (const float4*)&W2s[cls][0] + (half ? QB_B : 0);
            const float4* s4 = (const float4*)&Ss[wv * BPW + sub][0] + (half ? QB_B : 0);
            int q = 0;
            for (; q + 8 <= qcnt; q += 8) {
                float4 w[8], s[8];
#pragma unroll
                for (int u = 0; u < 8; ++u) { w[u] = w4[q + u]; s[u] = s4[q + u]; }
#pragma unroll
                for (int u = 0; u < 8; ++u) {
                    csum = fmaf(s[u].x, w[u].x, csum);
                    csum = fmaf(s[u].y, w[u].y, csum);
                    csum = fmaf(s[u].z, w[u].z, csum);
                    csum = fmaf(s[u].w, w[u].w, csum);
                }
            }
            for (; q < qcnt; ++q) {      // remainder (panel B: 3 quads)
                float4 w = w4[q];
                float4 s = s4[q];
                csum = fmaf(s.x, w.x, csum);
                csum = fmaf(s.y, w.y, csum);
                csum = fmaf(s.z, w.z, csum);
                csum = fmaf(s.w, w.w, csum);
            }
        }
        float csumB = __shfl_xor(csum, 32, 64);   // panel-A lane gets its B sum
        if (half == 0 && lact) {
            float ctot = __fadd_rn(csum, csumB);  // single panel-merge add
            float dec = __fmul_rn(__fmul_rn(h2m, 0.2f), (1.0f - h2s));
            float m = __fadd_rn(dec, fmaxf(ctot, 0.0f));
            float s = (m > 0.5f) ? 1.0f : 0.0f;
            h2m = m; h2s = s;
            acc = __fadd_rn(acc, s);              // small-int adds, exact
        }
        __syncthreads();   // protect Ss against next-iteration overwrite
    }

    if (t0 + ct >= T_TOT) {
        if (half == 0 && lact)
            out[(size_t)(bb + sub) * NCLS + cls] = __fdiv_rn(acc, 50.0f);
    } else {
#pragma unroll
        for (int u = 0; u < 2; ++u)
#pragma unroll
        for (int i = 0; i < 10; ++i) {
            int k = i * 64 + lane;
            if (k < NH) {
                st_h1m[(size_t)(bb + u) * NH + k] = h1m[u * 10 + i];
                st_h1s[(size_t)(bb + u) * NH + k] = h1s[u * 10 + i];
            }
        }
        if (half == 0 && lact) {
            int b2 = bb + sub;
            st_h2m[(size_t)b2 * NCLS + cls] = h2m;
            st_h2s[(size_t)b2 * NCLS + cls] = h2s;
            st_acc[(size_t)b2 * NCLS + cls] = acc;
        }
    }
}

// ---------------------------------------------------------------------------
extern "C" void kernel_launch(void* const* d_in, const int* in_sizes, int n_in,
                              void* d_out, int out_size, void* d_ws, size_t ws_size,
                              hipStream_t stream)
{
    const float* X  = (const float*)d_in[0];   // (2048, 50, 620) fp32
    const float* W1 = (const float*)d_in[1];   // (620, 620)
    const float* W2 = (const float*)d_in[2];   // (11, 620)
    float* out = (float*)d_out;                // (2048, 11) fp32

    const size_t state_floats = (size_t)2 * B_TOT * NH + (size_t)3 * B_TOT * NCLS;
    const size_t state_bytes  = state_floats * sizeof(float);
    const size_t bytes_per_t  = (size_t)B_TOT * NH * sizeof(float);

    size_t avail = (ws_size > state_bytes) ? (ws_size - state_bytes) : 0;
    int chunkT = (int)(avail / bytes_per_t);
    if (chunkT > T_TOT) chunkT = T_TOT;
    if (chunkT < 1) chunkT = 1;   // requires ws_size >= ~15.6 MB

    float* state = (float*)d_ws;
    float* Zbuf  = state + state_floats;

    for (int t0 = 0; t0 < T_TOT; t0 += chunkT) {
        int ct = (T_TOT - t0 < chunkT) ? (T_TOT - t0) : chunkT;
        dim3 ggrid((NH + BN - 1) / BN, (B_TOT * ct) / BM);
        gemm_relu_kernel<<<ggrid, 256, 0, stream>>>(X, W1, Zbuf, t0, ct);
        snn_kernel<<<dim3(B_TOT / BPB), 256, 0, stream>>>(Zbuf, W2, state, out, t0, ct);
    }
}